// Round 1
// baseline (1059.436 us; speedup 1.0000x reference)
//
#include <hip/hip_runtime.h>

// SymmetricGrpEquivLinear: out[k,a*64+b] = sum_{c,d} W[(a,b),(c,d)] * X[k,c*64+d]
// with W = sum_w weights[w] * B[w], B = set-partition masks over (a,b,c,d).
// Closed form (weight order traced from _set_partitions([0,1,2,3])):
//   w0 : a=b=c=d   -> [a==b] D[a]
//   w1 : b=c=d     -> D[b]
//   w2 : ab|cd     -> [a==b] T
//   w3 : a=c=d     -> D[a]
//   w4 : cd        -> T
//   w5 : a=b=c     -> [a==b] R[a]
//   w6 : bc|ad     -> X[b,a]
//   w7 : bc        -> R[b]
//   w8 : ac|bd     -> X[a,b]
//   w9 : a=b=d     -> [a==b] C[a]
//   w10: bd        -> C[b]
//   w11: ab        -> [a==b] S
//   w12: ac        -> R[a]
//   w13: ad        -> C[a]
//   w14: 1         -> S
// where (per batch element k): S=sum X, T=trace, R=row sums, C=col sums, D=diag.

__global__ __launch_bounds__(256) void sym_equiv_kernel(
    const float* __restrict__ X,
    const float* __restrict__ w,
    float* __restrict__ out)
{
    const int k   = blockIdx.x;
    const int tid = threadIdx.x;

    __shared__ float sX[64 * 65];          // stride 65: conflict-free row & col walks
    __shared__ float sR[64];
    __shared__ float sC[64];
    __shared__ float sD[64];
    __shared__ float sw[15];
    __shared__ float sScal[2];             // S, T

    if (tid < 15) sw[tid] = w[tid];

    // ---- stage X[k] (4096 floats) into LDS, float4-coalesced ----
    const float4* X4 = reinterpret_cast<const float4*>(X + (size_t)k * 4096);
    float4 v[4];
#pragma unroll
    for (int j = 0; j < 4; ++j) v[j] = X4[j * 256 + tid];
#pragma unroll
    for (int j = 0; j < 4; ++j) {
        const int base = j * 1024 + tid * 4;      // flat index, col%4 == 0
        const int row  = base >> 6;
        const int col  = base & 63;
        float* p = &sX[row * 65 + col];
        p[0] = v[j].x; p[1] = v[j].y; p[2] = v[j].z; p[3] = v[j].w;
    }
    __syncthreads();

    // ---- row sums R[c], col sums C[c]: 4 lanes per c, shuffle-combine ----
    {
        const int c = tid >> 2;                   // 0..63
        const int q = tid & 3;                    // 0..3
        float r = 0.f, cc = 0.f;
#pragma unroll
        for (int dd = 0; dd < 16; ++dd) {
            const int d = q * 16 + dd;
            r  += sX[c * 65 + d];
            cc += sX[d * 65 + c];
        }
        r  += __shfl_down(r, 1);  r  += __shfl_down(r, 2);
        cc += __shfl_down(cc, 1); cc += __shfl_down(cc, 2);
        if (q == 0) { sR[c] = r; sC[c] = cc; }
        if (tid < 64) sD[tid] = sX[tid * 65 + tid];
    }
    __syncthreads();

    // ---- S = sum R, T = sum D: single-wave butterfly ----
    if (tid < 64) {
        float s = sR[tid];
        float t = sD[tid];
#pragma unroll
        for (int off = 32; off > 0; off >>= 1) {
            s += __shfl_down(s, off);
            t += __shfl_down(t, off);
        }
        if (tid == 0) { sScal[0] = s; sScal[1] = t; }
    }
    __syncthreads();

    const float S = sScal[0], T = sScal[1];
    const float w0  = sw[0],  w1  = sw[1],  w2  = sw[2],  w3  = sw[3];
    const float w4  = sw[4],  w5  = sw[5],  w6  = sw[6],  w7  = sw[7];
    const float w8  = sw[8],  w9  = sw[9],  w10 = sw[10], w11 = sw[11];
    const float w12 = sw[12], w13 = sw[13], w14 = sw[14];

    const float cbase = w14 * S + w4 * T;

    // ---- emit out[k], float4-coalesced ----
    float4* O4 = reinterpret_cast<float4*>(out + (size_t)k * 4096);
#pragma unroll
    for (int j = 0; j < 4; ++j) {
        const int base = j * 1024 + tid * 4;
        const int a  = base >> 6;
        const int b0 = base & 63;                 // all 4 elems share row a
        const float Aa    = cbase + w12 * sR[a] + w13 * sC[a] + w3 * sD[a];
        const float diagv = w11 * S + w2 * T + w5 * sR[a] + w9 * sC[a] + w0 * sD[a];
        float o[4];
#pragma unroll
        for (int e = 0; e < 4; ++e) {
            const int b = b0 + e;
            float val = Aa
                      + w7  * sR[b] + w10 * sC[b] + w1 * sD[b]
                      + w8  * sX[a * 65 + b]
                      + w6  * sX[b * 65 + a];
            if (a == b) val += diagv;
            o[e] = val;
        }
        float4 ov;
        ov.x = o[0]; ov.y = o[1]; ov.z = o[2]; ov.w = o[3];
        O4[j * 256 + tid] = ov;
    }
}

extern "C" void kernel_launch(void* const* d_in, const int* in_sizes, int n_in,
                              void* d_out, int out_size, void* d_ws, size_t ws_size,
                              hipStream_t stream) {
    const float* X   = (const float*)d_in[0];   // (1024, 4096)
    const float* wts = (const float*)d_in[1];   // (15,)
    // d_in[2] = B (15,4096,4096) -- structurally known, never read
    float* out = (float*)d_out;                 // (1024, 4096)

    sym_equiv_kernel<<<dim3(1024), dim3(256), 0, stream>>>(X, wts, out);
}